// Round 2
// baseline (366.248 us; speedup 1.0000x reference)
//
#include <hip/hip_runtime.h>

#define N_NODES 100000
#define EMB 64
#define N_EDGES 1280000
#define N_E4 (N_EDGES / 4)     // 320000 int4 groups
#define SCAN_TILE 1024          // nodes per scan block (256 threads x 4)

// counting-sort CSR build (no global atomics)
#define NBUCK 196               // buckets of 512 nodes: dst >> 9
#define BUCK_SHIFT 9
#define BUCK_NODES 512
#define EPB 4096                // edges per pass-A block (256 thr x 4 int4)
#define NBA 313                 // ceil(N_EDGES / EPB)

typedef unsigned long long u64;
typedef _Float16 f16;
typedef __attribute__((ext_vector_type(2))) _Float16 f16x2;

// ---- A1: per-block bucket histogram (LDS atomics only) ----
__global__ void bucket_hist_kernel(const int* __restrict__ dst, int* __restrict__ hist) {
    __shared__ int lh[NBUCK];
    for (int i = threadIdx.x; i < NBUCK; i += 256) lh[i] = 0;
    __syncthreads();
#pragma unroll
    for (int k = 0; k < 4; ++k) {
        int q = blockIdx.x * 1024 + k * 256 + threadIdx.x;  // int4 index, coalesced
        if (q < N_E4) {
            int4 d4 = ((const int4*)dst)[q];
            atomicAdd(&lh[d4.x >> BUCK_SHIFT], 1);
            atomicAdd(&lh[d4.y >> BUCK_SHIFT], 1);
            atomicAdd(&lh[d4.z >> BUCK_SHIFT], 1);
            atomicAdd(&lh[d4.w >> BUCK_SHIFT], 1);
        }
    }
    __syncthreads();
    for (int i = threadIdx.x; i < NBUCK; i += 256)
        hist[i * NBA + blockIdx.x] = lh[i];   // bucket-major layout for the scan
}

// ---- A2: exclusive scan of hist (NBUCK*NBA = 61348 entries), single block ----
__global__ void bucket_scan_kernel(int* __restrict__ hist) {
    const int TOT = NBUCK * NBA;
    __shared__ int lds[1024];
    int per = (TOT + 1023) / 1024;           // 60
    int beg = threadIdx.x * per;
    int end = beg + per; if (end > TOT) end = TOT;
    int s = 0;
    for (int i = beg; i < end && i < TOT; ++i) s += hist[i];
    lds[threadIdx.x] = s;
    __syncthreads();
    for (int off = 1; off < 1024; off <<= 1) {
        int v = (threadIdx.x >= (unsigned)off) ? lds[threadIdx.x - off] : 0;
        __syncthreads();
        lds[threadIdx.x] += v;
        __syncthreads();
    }
    int run = lds[threadIdx.x] - s;          // exclusive base for this thread's range
    for (int i = beg; i < end && i < TOT; ++i) {
        int v = hist[i];
        hist[i] = run;
        run += v;
    }
}

// ---- A3: scatter edges into bucket-contiguous arrays (LDS cursors) ----
__global__ void bucket_scatter_kernel(const int* __restrict__ src, const int* __restrict__ dst,
                                      const int* __restrict__ hist,
                                      int* __restrict__ bsrc, int* __restrict__ bdst) {
    __shared__ int cur[NBUCK];
    for (int i = threadIdx.x; i < NBUCK; i += 256)
        cur[i] = hist[i * NBA + blockIdx.x];
    __syncthreads();
#pragma unroll
    for (int k = 0; k < 4; ++k) {
        int q = blockIdx.x * 1024 + k * 256 + threadIdx.x;
        if (q < N_E4) {
            int4 d4 = ((const int4*)dst)[q];
            int4 s4 = ((const int4*)src)[q];
            int p;
            p = atomicAdd(&cur[d4.x >> BUCK_SHIFT], 1); bsrc[p] = s4.x; bdst[p] = d4.x;
            p = atomicAdd(&cur[d4.y >> BUCK_SHIFT], 1); bsrc[p] = s4.y; bdst[p] = d4.y;
            p = atomicAdd(&cur[d4.z >> BUCK_SHIFT], 1); bsrc[p] = s4.z; bdst[p] = d4.z;
            p = atomicAdd(&cur[d4.w >> BUCK_SHIFT], 1); bsrc[p] = s4.w; bdst[p] = d4.w;
        }
    }
}

// ---- B1: per-bucket node histogram; LDS atomic RETURN = per-node rank.
// Each node lives in exactly one bucket -> deg written without global atomics. ----
__global__ void bucket_rank_kernel(const int* __restrict__ hist, const int* __restrict__ bdst,
                                   int* __restrict__ brank, int* __restrict__ deg) {
    __shared__ int lh[BUCK_NODES];
    int k = blockIdx.x;
    int beg = hist[k * NBA];
    int end = (k + 1 < NBUCK) ? hist[(k + 1) * NBA] : N_EDGES;
    for (int i = threadIdx.x; i < BUCK_NODES; i += 256) lh[i] = 0;
    __syncthreads();
    for (int i = beg + threadIdx.x; i < end; i += 256) {
        int d = bdst[i];
        brank[i] = atomicAdd(&lh[d & (BUCK_NODES - 1)], 1);
    }
    __syncthreads();
    int nbase = k * BUCK_NODES;
    for (int i = threadIdx.x; i < BUCK_NODES; i += 256)
        if (nbase + i < N_NODES) deg[nbase + i] = lh[i];
}

// ---- B2: CSR fill, atomic-free; bucket-local row_start gathers + col writes ----
__global__ void csr_fill_kernel(const int* __restrict__ row_start, const int* __restrict__ bdst,
                                const int* __restrict__ brank, const int* __restrict__ bsrc,
                                int* __restrict__ col) {
    int q = blockIdx.x * blockDim.x + threadIdx.x;
    if (q < N_E4) {
        int4 d4 = ((const int4*)bdst)[q];
        int4 r4 = ((const int4*)brank)[q];
        int4 s4 = ((const int4*)bsrc)[q];
        col[row_start[d4.x] + r4.x] = s4.x;
        col[row_start[d4.y] + r4.y] = s4.y;
        col[row_start[d4.z] + r4.z] = s4.z;
        col[row_start[d4.w] + r4.w] = s4.w;
    }
}

// ---- dinv = deg^-0.5, rdinv = deg^0.5 (both 0 where deg==0) ----
__global__ void norm_kernel(const int* __restrict__ deg, float* __restrict__ dinv,
                            float* __restrict__ rdinv) {
    int i = blockIdx.x * blockDim.x + threadIdx.x;
    if (i < N_NODES) {
        int d = deg[i];
        float fd = (float)d;
        dinv[i]  = (d > 0) ? rsqrtf(fd) : 0.0f;
        rdinv[i] = (d > 0) ? sqrtf(fd) : 0.0f;
    }
}

// ---- y0 = dinv * emb, fp16, cached store (y0 is gathered next -> keep in L2/L3) ----
__global__ void y0_kernel(const float* __restrict__ emb, const float* __restrict__ dinv,
                          f16* __restrict__ y0) {
    int i = blockIdx.x * blockDim.x + threadIdx.x;
    const int n4 = N_NODES * EMB / 4;
    if (i < n4) {
        float dv = dinv[i >> 4];  // 16 float4s per 64-dim row
        float4 v = ((const float4*)emb)[i];
        f16 h[4] = {(f16)(v.x * dv), (f16)(v.y * dv), (f16)(v.z * dv), (f16)(v.w * dv)};
        ((u64*)y0)[i] = *(const u64*)h;
    }
}

// ---- scan pass 1: per-block local exclusive scan + block sums ----
__global__ void scan1_kernel(const int* __restrict__ deg, int* __restrict__ local_scan,
                             int* __restrict__ block_sums) {
    __shared__ int lds[256];
    int base = blockIdx.x * SCAN_TILE;
    int vals[4];
    int tsum = 0;
#pragma unroll
    for (int k = 0; k < 4; ++k) {
        int i = base + threadIdx.x * 4 + k;
        vals[k] = (i < N_NODES) ? deg[i] : 0;
        tsum += vals[k];
    }
    lds[threadIdx.x] = tsum;
    __syncthreads();
    for (int off = 1; off < 256; off <<= 1) {
        int v = (threadIdx.x >= (unsigned)off) ? lds[threadIdx.x - off] : 0;
        __syncthreads();
        lds[threadIdx.x] += v;
        __syncthreads();
    }
    int texcl = lds[threadIdx.x] - tsum;
    if (threadIdx.x == 255) block_sums[blockIdx.x] = lds[255];
    int run = texcl;
#pragma unroll
    for (int k = 0; k < 4; ++k) {
        int i = base + threadIdx.x * 4 + k;
        if (i < N_NODES) local_scan[i] = run;
        run += vals[k];
    }
}

// ---- scan pass 2: exclusive scan of the 98 block sums (single block) ----
__global__ void scan2_kernel(int* __restrict__ block_sums, int nb) {
    __shared__ int lds[128];
    int v = (threadIdx.x < (unsigned)nb) ? block_sums[threadIdx.x] : 0;
    lds[threadIdx.x] = v;
    __syncthreads();
    for (int off = 1; off < 128; off <<= 1) {
        int t = (threadIdx.x >= (unsigned)off) ? lds[threadIdx.x - off] : 0;
        __syncthreads();
        lds[threadIdx.x] += t;
        __syncthreads();
    }
    if (threadIdx.x < (unsigned)nb) block_sums[threadIdx.x] = lds[threadIdx.x] - v;
}

// ---- scan pass 3: add block offsets; cap row_start ----
__global__ void scan3_kernel(int* __restrict__ row_start, const int* __restrict__ block_sums) {
    int i = blockIdx.x * blockDim.x + threadIdx.x;
    if (i < N_NODES) {
        row_start[i] = row_start[i] + block_sums[i / SCAN_TILE];
    }
    if (i == 0) row_start[N_NODES] = N_EDGES;
}

// ---- propagation: one wave per destination row, two slots, 8-deep MLP ----
// Lane = (slot s, dim-pair j). All __shfl ops exec-uniform (R9 lesson).
// ALL loads/stores cached (except final out): y layers live in L2/L3 so the
// random 128 B row gathers are L3 hits, not ~900-cycle HBM misses.
template <bool FINAL>
__global__ void gather_kernel(const int* __restrict__ row_start, const int* __restrict__ col,
                              const float* __restrict__ dinv, const float* __restrict__ rdinv,
                              const f16* __restrict__ yin, f16* __restrict__ yout,
                              const float* __restrict__ emb,
                              const f16* __restrict__ y1, const f16* __restrict__ y2,
                              float* __restrict__ out) {
    unsigned int gid = blockIdx.x * blockDim.x + threadIdx.x;
    unsigned int row = gid >> 6;       // wave-uniform
    int lane = (int)(gid & 63u);
    int s = lane >> 5;   // edge slot 0/1
    int j = lane & 31;   // dim pair: dims 2j, 2j+1
    if (row >= N_NODES) return;        // wave-uniform exit
    int beg = row_start[row];
    int end = row_start[row + 1];
    const f16* yj = yin + 2 * j;       // lane-fixed dim offset
    float accx = 0.0f, accy = 0.0f;
    for (int cb = beg; cb < end; cb += 64) {   // uniform bounds
        int idx = cb + lane;
        int ci = 0;
        if (idx < end) ci = col[idx];
        int n = end - cb;
        if (n > 64) n = 64;            // uniform
        int kk = 0;
        for (; kk + 8 <= n; kk += 8) { // 4 edges per slot: 8 gathers in flight/wave
            int c0 = __shfl(ci, kk + s);
            int c1 = __shfl(ci, kk + s + 2);
            int c2 = __shfl(ci, kk + s + 4);
            int c3 = __shfl(ci, kk + s + 6);
            unsigned u0 = *(const unsigned*)(yj + (unsigned)c0 * EMB);
            unsigned u1 = *(const unsigned*)(yj + (unsigned)c1 * EMB);
            unsigned u2 = *(const unsigned*)(yj + (unsigned)c2 * EMB);
            unsigned u3 = *(const unsigned*)(yj + (unsigned)c3 * EMB);
            f16x2 h0 = __builtin_bit_cast(f16x2, u0);
            f16x2 h1 = __builtin_bit_cast(f16x2, u1);
            f16x2 h2 = __builtin_bit_cast(f16x2, u2);
            f16x2 h3 = __builtin_bit_cast(f16x2, u3);
            accx += (float)h0.x + (float)h1.x + (float)h2.x + (float)h3.x;
            accy += (float)h0.y + (float)h1.y + (float)h2.y + (float)h3.y;
        }
        if (kk + 4 <= n) {             // uniform
            int c0 = __shfl(ci, kk + s);
            int c1 = __shfl(ci, kk + s + 2);
            unsigned u0 = *(const unsigned*)(yj + (unsigned)c0 * EMB);
            unsigned u1 = *(const unsigned*)(yj + (unsigned)c1 * EMB);
            f16x2 h0 = __builtin_bit_cast(f16x2, u0);
            f16x2 h1 = __builtin_bit_cast(f16x2, u1);
            accx += (float)h0.x + (float)h1.x;
            accy += (float)h0.y + (float)h1.y;
            kk += 4;
        }
        for (; kk < n; ++kk) {         // <=3 edges; shfl converged, acc predicated
            int c = __shfl(ci, kk);
            if (s == (kk & 1)) {
                unsigned u = *(const unsigned*)(yj + (unsigned)c * EMB);
                f16x2 h = __builtin_bit_cast(f16x2, u);
                accx += (float)h.x;
                accy += (float)h.y;
            }
        }
    }
    // merge the two edge slots (converged)
    accx += __shfl_xor(accx, 32);
    accy += __shfl_xor(accy, 32);
    if (s == 0) {
        float dv = dinv[row];
        unsigned int o = row * EMB + 2 * (unsigned)j;
        if (!FINAL) {
            float sc = dv * dv;
            f16x2 h;
            h.x = (f16)(accx * sc);
            h.y = (f16)(accy * sc);
            *(unsigned*)(yout + o) = __builtin_bit_cast(unsigned, h);  // cached: re-read next layer
        } else {
            float rv = rdinv[row];
            float2 e2 = *(const float2*)(emb + o);
            f16x2 a = __builtin_bit_cast(f16x2, *(const unsigned*)(y1 + o));
            f16x2 b = __builtin_bit_cast(f16x2, *(const unsigned*)(y2 + o));
            float rx = 0.25f * (e2.x + rv * ((float)a.x + (float)b.x) + dv * accx);
            float ry = 0.25f * (e2.y + rv * ((float)a.y + (float)b.y) + dv * accy);
            __builtin_nontemporal_store(rx, out + o);      // out is never re-read
            __builtin_nontemporal_store(ry, out + o + 1);
        }
    }
}

extern "C" void kernel_launch(void* const* d_in, const int* in_sizes, int n_in,
                              void* d_out, int out_size, void* d_ws, size_t ws_size,
                              hipStream_t stream) {
    const int*   edge = (const int*)d_in[0];   // (2, N_EDGES) row-major
    const int*   src  = edge;
    const int*   dst  = edge + N_EDGES;
    const float* emb  = (const float*)d_in[1]; // (N_NODES, 64) fp32
    float*       out  = (float*)d_out;

    // workspace carve (16B-aligned offsets)
    char* ws = (char*)d_ws;
    size_t off = 0;
    int* deg       = (int*)(ws + off); off += 400000;
    int* row_start = (int*)(ws + off); off += 400016;
    int* bsums     = (int*)(ws + off); off += 512;
    float* dinv    = (float*)(ws + off); off += 400000;
    float* rdinv   = (float*)(ws + off); off += 400000;
    int* hist      = (int*)(ws + off); off += (size_t)NBUCK * NBA * 4 + 16; // 245 KB
    int* col       = (int*)(ws + off); off += (size_t)N_EDGES * 4;          // 5.12 MB
    f16* y0        = (f16*)(ws + off); off += (size_t)N_NODES * EMB * 2;    // 12.8 MB
    f16* y1        = (f16*)(ws + off); off += (size_t)N_NODES * EMB * 2;    // 12.8 MB
    f16* y2        = (f16*)(ws + off); off += (size_t)N_NODES * EMB * 2;    // 12.8 MB

    // bucketed edge arrays alias y1/y2: all dead before the first gather writes y1
    // (layer 1) and before layer 2 writes y2.
    int* bsrc  = (int*)y1;                       // 5.12 MB
    int* bdst  = (int*)((char*)y1 + (size_t)N_EDGES * 4); // 5.12 MB (y1 is 12.8 MB)
    int* brank = (int*)y2;                       // 5.12 MB

    const int NB = (N_NODES + SCAN_TILE - 1) / SCAN_TILE;  // 98

    // ---- CSR build via bucketed counting sort: zero global atomics ----
    bucket_hist_kernel<<<NBA, 256, 0, stream>>>(dst, hist);
    bucket_scan_kernel<<<1, 1024, 0, stream>>>(hist);
    bucket_scatter_kernel<<<NBA, 256, 0, stream>>>(src, dst, hist, bsrc, bdst);
    bucket_rank_kernel<<<NBUCK, 256, 0, stream>>>(hist, bdst, brank, deg);
    norm_kernel<<<(N_NODES + 255) / 256, 256, 0, stream>>>(deg, dinv, rdinv);
    y0_kernel<<<(N_NODES * EMB / 4 + 255) / 256, 256, 0, stream>>>(emb, dinv, y0);
    scan1_kernel<<<NB, 256, 0, stream>>>(deg, row_start, bsums);
    scan2_kernel<<<1, 128, 0, stream>>>(bsums, NB);
    scan3_kernel<<<(N_NODES + 255) / 256, 256, 0, stream>>>(row_start, bsums);
    csr_fill_kernel<<<(N_E4 + 255) / 256, 256, 0, stream>>>(row_start, bdst, brank,
                                                            bsrc, col);

    // ---- 3 propagation layers (pure y-sums), final fuses the 1/4-sum ----
    const unsigned int gthreads = (unsigned int)N_NODES * EMB;
    const int gblocks = (int)((gthreads + 255) / 256);
    gather_kernel<false><<<gblocks, 256, 0, stream>>>(row_start, col, dinv, rdinv,
                                                      y0, y1, emb, y1, y2, out);
    gather_kernel<false><<<gblocks, 256, 0, stream>>>(row_start, col, dinv, rdinv,
                                                      y1, y2, emb, y1, y2, out);
    gather_kernel<true><<<gblocks, 256, 0, stream>>>(row_start, col, dinv, rdinv,
                                                     y2, (f16*)0, emb, y1, y2, out);
}

// Round 3
// 285.632 us; speedup vs baseline: 1.2822x; 1.2822x over previous
//
#include <hip/hip_runtime.h>

#define N_NODES 100000
#define EMB 64
#define N_EDGES 1280000
#define N_E4 (N_EDGES / 4)     // 320000 int4 groups
#define SCAN_TILE 1024          // nodes per scan block (256 threads x 4)

// counting-sort CSR build (no global atomics)
#define NBUCK 196               // buckets of 512 nodes: dst >> 9
#define BUCK_SHIFT 9
#define BUCK_NODES 512
#define EPB 4096                // edges per pass-A block (256 thr x 4 int4)
#define NBA 313                 // ceil(N_EDGES / EPB)
#define HTOT (NBUCK * NBA)      // 61348 hist entries
#define NBH ((HTOT + 1023) / 1024)  // 60 hist-scan blocks

typedef unsigned long long u64;
typedef _Float16 f16;
typedef __attribute__((ext_vector_type(2))) _Float16 f16x2;

// ---- A1: per-block bucket histogram (LDS atomics only) ----
__global__ void bucket_hist_kernel(const int* __restrict__ dst, int* __restrict__ hist) {
    __shared__ int lh[NBUCK];
    for (int i = threadIdx.x; i < NBUCK; i += 256) lh[i] = 0;
    __syncthreads();
#pragma unroll
    for (int k = 0; k < 4; ++k) {
        int q = blockIdx.x * 1024 + k * 256 + threadIdx.x;  // int4 index, coalesced
        if (q < N_E4) {
            int4 d4 = ((const int4*)dst)[q];
            atomicAdd(&lh[d4.x >> BUCK_SHIFT], 1);
            atomicAdd(&lh[d4.y >> BUCK_SHIFT], 1);
            atomicAdd(&lh[d4.z >> BUCK_SHIFT], 1);
            atomicAdd(&lh[d4.w >> BUCK_SHIFT], 1);
        }
    }
    __syncthreads();
    for (int i = threadIdx.x; i < NBUCK; i += 256)
        hist[i * NBA + blockIdx.x] = lh[i];   // bucket-major layout for the scan
}

// ---- A2a: hierarchical scan pass 1 over hist (in-place) + block sums ----
__global__ void hist_scan1_kernel(int* __restrict__ hist, int* __restrict__ hbs) {
    __shared__ int lds[256];
    int base = blockIdx.x * 1024;
    int vals[4];
    int tsum = 0;
#pragma unroll
    for (int k = 0; k < 4; ++k) {
        int i = base + threadIdx.x * 4 + k;
        vals[k] = (i < HTOT) ? hist[i] : 0;
        tsum += vals[k];
    }
    lds[threadIdx.x] = tsum;
    __syncthreads();
    for (int off = 1; off < 256; off <<= 1) {
        int v = (threadIdx.x >= (unsigned)off) ? lds[threadIdx.x - off] : 0;
        __syncthreads();
        lds[threadIdx.x] += v;
        __syncthreads();
    }
    int run = lds[threadIdx.x] - tsum;      // local exclusive base
    if (threadIdx.x == 255) hbs[blockIdx.x] = lds[255];
    #pragma unroll
    for (int k = 0; k < 4; ++k) {
        int i = base + threadIdx.x * 4 + k;
        if (i < HTOT) hist[i] = run;        // in-place: own entries only
        run += vals[k];
    }
}

// ---- A2b: exclusive scan of the 60 hist block sums (tiny) ----
// Consumers (A3, B1) add hbs[idx>>10] at read time -> no third pass.
__global__ void hist_scan2_kernel(int* __restrict__ hbs) {
    __shared__ int lds[64];
    int v = (threadIdx.x < (unsigned)NBH) ? hbs[threadIdx.x] : 0;
    lds[threadIdx.x] = v;
    __syncthreads();
    for (int off = 1; off < 64; off <<= 1) {
        int t = (threadIdx.x >= (unsigned)off) ? lds[threadIdx.x - off] : 0;
        __syncthreads();
        lds[threadIdx.x] += t;
        __syncthreads();
    }
    if (threadIdx.x < (unsigned)NBH) hbs[threadIdx.x] = lds[threadIdx.x] - v;
}

// ---- A3: scatter edges into bucket-contiguous arrays (LDS cursors) ----
__global__ void bucket_scatter_kernel(const int* __restrict__ src, const int* __restrict__ dst,
                                      const int* __restrict__ hist, const int* __restrict__ hbs,
                                      int* __restrict__ bsrc, int* __restrict__ bdst) {
    __shared__ int cur[NBUCK];
    for (int i = threadIdx.x; i < NBUCK; i += 256) {
        int idx = i * NBA + blockIdx.x;
        cur[i] = hist[idx] + hbs[idx >> 10];
    }
    __syncthreads();
#pragma unroll
    for (int k = 0; k < 4; ++k) {
        int q = blockIdx.x * 1024 + k * 256 + threadIdx.x;
        if (q < N_E4) {
            int4 d4 = ((const int4*)dst)[q];
            int4 s4 = ((const int4*)src)[q];
            int p;
            p = atomicAdd(&cur[d4.x >> BUCK_SHIFT], 1); bsrc[p] = s4.x; bdst[p] = d4.x;
            p = atomicAdd(&cur[d4.y >> BUCK_SHIFT], 1); bsrc[p] = s4.y; bdst[p] = d4.y;
            p = atomicAdd(&cur[d4.z >> BUCK_SHIFT], 1); bsrc[p] = s4.z; bdst[p] = d4.z;
            p = atomicAdd(&cur[d4.w >> BUCK_SHIFT], 1); bsrc[p] = s4.w; bdst[p] = d4.w;
        }
    }
}

// ---- B1: per-bucket node histogram; LDS atomic RETURN = per-node rank.
// Each node lives in exactly one bucket -> deg written without global atomics. ----
__global__ void bucket_rank_kernel(const int* __restrict__ hist, const int* __restrict__ hbs,
                                   const int* __restrict__ bdst,
                                   int* __restrict__ brank, int* __restrict__ deg) {
    __shared__ int lh[BUCK_NODES];
    int k = blockIdx.x;
    int i0 = k * NBA;
    int beg = hist[i0] + hbs[i0 >> 10];
    int end;
    if (k + 1 < NBUCK) {
        int i1 = (k + 1) * NBA;
        end = hist[i1] + hbs[i1 >> 10];
    } else {
        end = N_EDGES;
    }
    for (int i = threadIdx.x; i < BUCK_NODES; i += 256) lh[i] = 0;
    __syncthreads();
    for (int i = beg + threadIdx.x; i < end; i += 256) {
        int d = bdst[i];
        brank[i] = atomicAdd(&lh[d & (BUCK_NODES - 1)], 1);
    }
    __syncthreads();
    int nbase = k * BUCK_NODES;
    for (int i = threadIdx.x; i < BUCK_NODES; i += 256)
        if (nbase + i < N_NODES) deg[nbase + i] = lh[i];
}

// ---- B2: CSR fill, atomic-free; bucket-local row_start gathers + col writes ----
__global__ void csr_fill_kernel(const int* __restrict__ row_start, const int* __restrict__ bdst,
                                const int* __restrict__ brank, const int* __restrict__ bsrc,
                                int* __restrict__ col) {
    int q = blockIdx.x * blockDim.x + threadIdx.x;
    if (q < N_E4) {
        int4 d4 = ((const int4*)bdst)[q];
        int4 r4 = ((const int4*)brank)[q];
        int4 s4 = ((const int4*)bsrc)[q];
        col[row_start[d4.x] + r4.x] = s4.x;
        col[row_start[d4.y] + r4.y] = s4.y;
        col[row_start[d4.z] + r4.z] = s4.z;
        col[row_start[d4.w] + r4.w] = s4.w;
    }
}

// ---- dinv = deg^-0.5, rdinv = deg^0.5 (both 0 where deg==0) ----
__global__ void norm_kernel(const int* __restrict__ deg, float* __restrict__ dinv,
                            float* __restrict__ rdinv) {
    int i = blockIdx.x * blockDim.x + threadIdx.x;
    if (i < N_NODES) {
        int d = deg[i];
        float fd = (float)d;
        dinv[i]  = (d > 0) ? rsqrtf(fd) : 0.0f;
        rdinv[i] = (d > 0) ? sqrtf(fd) : 0.0f;
    }
}

// ---- y0 = dinv * emb, fp16, cached store (y0 is gathered next -> keep in L2/L3) ----
__global__ void y0_kernel(const float* __restrict__ emb, const float* __restrict__ dinv,
                          f16* __restrict__ y0) {
    int i = blockIdx.x * blockDim.x + threadIdx.x;
    const int n4 = N_NODES * EMB / 4;
    if (i < n4) {
        float dv = dinv[i >> 4];  // 16 float4s per 64-dim row
        float4 v = ((const float4*)emb)[i];
        f16 h[4] = {(f16)(v.x * dv), (f16)(v.y * dv), (f16)(v.z * dv), (f16)(v.w * dv)};
        ((u64*)y0)[i] = *(const u64*)h;
    }
}

// ---- scan pass 1: per-block local exclusive scan + block sums ----
__global__ void scan1_kernel(const int* __restrict__ deg, int* __restrict__ local_scan,
                             int* __restrict__ block_sums) {
    __shared__ int lds[256];
    int base = blockIdx.x * SCAN_TILE;
    int vals[4];
    int tsum = 0;
#pragma unroll
    for (int k = 0; k < 4; ++k) {
        int i = base + threadIdx.x * 4 + k;
        vals[k] = (i < N_NODES) ? deg[i] : 0;
        tsum += vals[k];
    }
    lds[threadIdx.x] = tsum;
    __syncthreads();
    for (int off = 1; off < 256; off <<= 1) {
        int v = (threadIdx.x >= (unsigned)off) ? lds[threadIdx.x - off] : 0;
        __syncthreads();
        lds[threadIdx.x] += v;
        __syncthreads();
    }
    int texcl = lds[threadIdx.x] - tsum;
    if (threadIdx.x == 255) block_sums[blockIdx.x] = lds[255];
    int run = texcl;
#pragma unroll
    for (int k = 0; k < 4; ++k) {
        int i = base + threadIdx.x * 4 + k;
        if (i < N_NODES) local_scan[i] = run;
        run += vals[k];
    }
}

// ---- scan pass 2: exclusive scan of the 98 block sums (single block) ----
__global__ void scan2_kernel(int* __restrict__ block_sums, int nb) {
    __shared__ int lds[128];
    int v = (threadIdx.x < (unsigned)nb) ? block_sums[threadIdx.x] : 0;
    lds[threadIdx.x] = v;
    __syncthreads();
    for (int off = 1; off < 128; off <<= 1) {
        int t = (threadIdx.x >= (unsigned)off) ? lds[threadIdx.x - off] : 0;
        __syncthreads();
        lds[threadIdx.x] += t;
        __syncthreads();
    }
    if (threadIdx.x < (unsigned)nb) block_sums[threadIdx.x] = lds[threadIdx.x] - v;
}

// ---- scan pass 3: add block offsets; cap row_start ----
__global__ void scan3_kernel(int* __restrict__ row_start, const int* __restrict__ block_sums) {
    int i = blockIdx.x * blockDim.x + threadIdx.x;
    if (i < N_NODES) {
        row_start[i] = row_start[i] + block_sums[i / SCAN_TILE];
    }
    if (i == 0) row_start[N_NODES] = N_EDGES;
}

// ---- propagation: one wave per destination row, two slots, 8-deep MLP ----
// Lane = (slot s, dim-pair j). All __shfl ops exec-uniform (R9 lesson).
// ALL loads/stores cached (except final out): y layers live in L2/L3 so the
// random 128 B row gathers are L3 hits, not ~900-cycle HBM misses.
template <bool FINAL>
__global__ void gather_kernel(const int* __restrict__ row_start, const int* __restrict__ col,
                              const float* __restrict__ dinv, const float* __restrict__ rdinv,
                              const f16* __restrict__ yin, f16* __restrict__ yout,
                              const float* __restrict__ emb,
                              const f16* __restrict__ y1, const f16* __restrict__ y2,
                              float* __restrict__ out) {
    unsigned int gid = blockIdx.x * blockDim.x + threadIdx.x;
    unsigned int row = gid >> 6;       // wave-uniform
    int lane = (int)(gid & 63u);
    int s = lane >> 5;   // edge slot 0/1
    int j = lane & 31;   // dim pair: dims 2j, 2j+1
    if (row >= N_NODES) return;        // wave-uniform exit
    int beg = row_start[row];
    int end = row_start[row + 1];
    const f16* yj = yin + 2 * j;       // lane-fixed dim offset
    float accx = 0.0f, accy = 0.0f;
    for (int cb = beg; cb < end; cb += 64) {   // uniform bounds
        int idx = cb + lane;
        int ci = 0;
        if (idx < end) ci = col[idx];
        int n = end - cb;
        if (n > 64) n = 64;            // uniform
        int kk = 0;
        for (; kk + 8 <= n; kk += 8) { // 4 edges per slot: 8 gathers in flight/wave
            int c0 = __shfl(ci, kk + s);
            int c1 = __shfl(ci, kk + s + 2);
            int c2 = __shfl(ci, kk + s + 4);
            int c3 = __shfl(ci, kk + s + 6);
            unsigned u0 = *(const unsigned*)(yj + (unsigned)c0 * EMB);
            unsigned u1 = *(const unsigned*)(yj + (unsigned)c1 * EMB);
            unsigned u2 = *(const unsigned*)(yj + (unsigned)c2 * EMB);
            unsigned u3 = *(const unsigned*)(yj + (unsigned)c3 * EMB);
            f16x2 h0 = __builtin_bit_cast(f16x2, u0);
            f16x2 h1 = __builtin_bit_cast(f16x2, u1);
            f16x2 h2 = __builtin_bit_cast(f16x2, u2);
            f16x2 h3 = __builtin_bit_cast(f16x2, u3);
            accx += (float)h0.x + (float)h1.x + (float)h2.x + (float)h3.x;
            accy += (float)h0.y + (float)h1.y + (float)h2.y + (float)h3.y;
        }
        if (kk + 4 <= n) {             // uniform
            int c0 = __shfl(ci, kk + s);
            int c1 = __shfl(ci, kk + s + 2);
            unsigned u0 = *(const unsigned*)(yj + (unsigned)c0 * EMB);
            unsigned u1 = *(const unsigned*)(yj + (unsigned)c1 * EMB);
            f16x2 h0 = __builtin_bit_cast(f16x2, u0);
            f16x2 h1 = __builtin_bit_cast(f16x2, u1);
            accx += (float)h0.x + (float)h1.x;
            accy += (float)h0.y + (float)h1.y;
            kk += 4;
        }
        for (; kk < n; ++kk) {         // <=3 edges; shfl converged, acc predicated
            int c = __shfl(ci, kk);
            if (s == (kk & 1)) {
                unsigned u = *(const unsigned*)(yj + (unsigned)c * EMB);
                f16x2 h = __builtin_bit_cast(f16x2, u);
                accx += (float)h.x;
                accy += (float)h.y;
            }
        }
    }
    // merge the two edge slots (converged)
    accx += __shfl_xor(accx, 32);
    accy += __shfl_xor(accy, 32);
    if (s == 0) {
        float dv = dinv[row];
        unsigned int o = row * EMB + 2 * (unsigned)j;
        if (!FINAL) {
            float sc = dv * dv;
            f16x2 h;
            h.x = (f16)(accx * sc);
            h.y = (f16)(accy * sc);
            *(unsigned*)(yout + o) = __builtin_bit_cast(unsigned, h);  // cached: re-read next layer
        } else {
            float rv = rdinv[row];
            float2 e2 = *(const float2*)(emb + o);
            f16x2 a = __builtin_bit_cast(f16x2, *(const unsigned*)(y1 + o));
            f16x2 b = __builtin_bit_cast(f16x2, *(const unsigned*)(y2 + o));
            float rx = 0.25f * (e2.x + rv * ((float)a.x + (float)b.x) + dv * accx);
            float ry = 0.25f * (e2.y + rv * ((float)a.y + (float)b.y) + dv * accy);
            __builtin_nontemporal_store(rx, out + o);      // out is never re-read
            __builtin_nontemporal_store(ry, out + o + 1);
        }
    }
}

extern "C" void kernel_launch(void* const* d_in, const int* in_sizes, int n_in,
                              void* d_out, int out_size, void* d_ws, size_t ws_size,
                              hipStream_t stream) {
    const int*   edge = (const int*)d_in[0];   // (2, N_EDGES) row-major
    const int*   src  = edge;
    const int*   dst  = edge + N_EDGES;
    const float* emb  = (const float*)d_in[1]; // (N_NODES, 64) fp32
    float*       out  = (float*)d_out;

    // workspace carve (16B-aligned offsets)
    char* ws = (char*)d_ws;
    size_t off = 0;
    int* deg       = (int*)(ws + off); off += 400000;
    int* row_start = (int*)(ws + off); off += 400016;
    int* bsums     = (int*)(ws + off); off += 512;
    int* hbs       = (int*)(ws + off); off += 256;   // hist-scan block sums (60)
    float* dinv    = (float*)(ws + off); off += 400000;
    float* rdinv   = (float*)(ws + off); off += 400000;
    int* hist      = (int*)(ws + off); off += (size_t)HTOT * 4 + 16;        // 245 KB
    int* col       = (int*)(ws + off); off += (size_t)N_EDGES * 4;          // 5.12 MB
    f16* y0        = (f16*)(ws + off); off += (size_t)N_NODES * EMB * 2;    // 12.8 MB
    f16* y1        = (f16*)(ws + off); off += (size_t)N_NODES * EMB * 2;    // 12.8 MB
    f16* y2        = (f16*)(ws + off); off += (size_t)N_NODES * EMB * 2;    // 12.8 MB

    // bucketed edge arrays alias y1/y2: all dead before the first gather writes y1
    // (layer 1) and before layer 2 writes y2.
    int* bsrc  = (int*)y1;                       // 5.12 MB
    int* bdst  = (int*)((char*)y1 + (size_t)N_EDGES * 4); // 5.12 MB (y1 is 12.8 MB)
    int* brank = (int*)y2;                       // 5.12 MB

    const int NB = (N_NODES + SCAN_TILE - 1) / SCAN_TILE;  // 98

    // ---- CSR build via bucketed counting sort: zero global atomics ----
    bucket_hist_kernel<<<NBA, 256, 0, stream>>>(dst, hist);
    hist_scan1_kernel<<<NBH, 256, 0, stream>>>(hist, hbs);
    hist_scan2_kernel<<<1, 64, 0, stream>>>(hbs);
    bucket_scatter_kernel<<<NBA, 256, 0, stream>>>(src, dst, hist, hbs, bsrc, bdst);
    bucket_rank_kernel<<<NBUCK, 256, 0, stream>>>(hist, hbs, bdst, brank, deg);
    norm_kernel<<<(N_NODES + 255) / 256, 256, 0, stream>>>(deg, dinv, rdinv);
    y0_kernel<<<(N_NODES * EMB / 4 + 255) / 256, 256, 0, stream>>>(emb, dinv, y0);
    scan1_kernel<<<NB, 256, 0, stream>>>(deg, row_start, bsums);
    scan2_kernel<<<1, 128, 0, stream>>>(bsums, NB);
    scan3_kernel<<<(N_NODES + 255) / 256, 256, 0, stream>>>(row_start, bsums);
    csr_fill_kernel<<<(N_E4 + 255) / 256, 256, 0, stream>>>(row_start, bdst, brank,
                                                            bsrc, col);

    // ---- 3 propagation layers (pure y-sums), final fuses the 1/4-sum ----
    const unsigned int gthreads = (unsigned int)N_NODES * EMB;
    const int gblocks = (int)((gthreads + 255) / 256);
    gather_kernel<false><<<gblocks, 256, 0, stream>>>(row_start, col, dinv, rdinv,
                                                      y0, y1, emb, y1, y2, out);
    gather_kernel<false><<<gblocks, 256, 0, stream>>>(row_start, col, dinv, rdinv,
                                                      y1, y2, emb, y1, y2, out);
    gather_kernel<true><<<gblocks, 256, 0, stream>>>(row_start, col, dinv, rdinv,
                                                     y2, (f16*)0, emb, y1, y2, out);
}